// Round 1
// baseline (20602.942 us; speedup 1.0000x reference)
//
#include <hip/hip_runtime.h>

constexpr int kB   = 32;    // batch
constexpr int kNS  = 100;   // n_support
constexpr int kNW  = 10;    // n_way
constexpr int kNZ  = 1000;  // kNS*kNW
constexpr int kD   = 512;   // feature dim
constexpr int kNQ  = 150;   // N*Q query rows
constexpr int kIt  = 15;    // IPM iterations

// -------------------------------------------------------------------------
// K[b][i][j] = <sup_i, sup_j>  (fp32 accumulate, stored fp64 for the IPM)
__global__ __launch_bounds__(128) void gram_kernel(const float* __restrict__ sup,
                                                   double* __restrict__ K64)
{
    const int i = blockIdx.x;
    const int b = blockIdx.y;
    const int tid = threadIdx.x;
    __shared__ float rowi[kD];
    const float* supb = sup + (size_t)b * kNS * kD;
    reinterpret_cast<float4*>(rowi)[tid] =
        reinterpret_cast<const float4*>(supb + (size_t)i * kD)[tid];
    __syncthreads();
    for (int j = tid; j < kNS; j += 128) {
        const float4* rj = reinterpret_cast<const float4*>(supb + (size_t)j * kD);
        float acc = 0.0f;
        for (int d4 = 0; d4 < kD / 4; ++d4) {
            float4 v = rj[d4];
            acc += rowi[4*d4+0]*v.x + rowi[4*d4+1]*v.y
                 + rowi[4*d4+2]*v.z + rowi[4*d4+3]*v.w;
        }
        K64[((size_t)b * kNS + i) * kNS + j] = (double)acc;
    }
}

// compat[b][i][q] = <sup_i, qry_q>
__global__ __launch_bounds__(256) void compat_kernel(const float* __restrict__ sup,
                                                     const float* __restrict__ qry,
                                                     float* __restrict__ compat)
{
    const int i = blockIdx.x;
    const int b = blockIdx.y;
    const int tid = threadIdx.x;
    __shared__ float rowi[kD];
    const float* supb = sup + (size_t)b * kNS * kD;
    const float* qryb = qry + (size_t)b * kNQ * kD;
    if (tid < 128)
        reinterpret_cast<float4*>(rowi)[tid] =
            reinterpret_cast<const float4*>(supb + (size_t)i * kD)[tid];
    __syncthreads();
    for (int j = tid; j < kNQ; j += 256) {
        const float4* rj = reinterpret_cast<const float4*>(qryb + (size_t)j * kD);
        float acc = 0.0f;
        for (int d4 = 0; d4 < kD / 4; ++d4) {
            float4 v = rj[d4];
            acc += rowi[4*d4+0]*v.x + rowi[4*d4+1]*v.y
                 + rowi[4*d4+2]*v.z + rowi[4*d4+3]*v.w;
        }
        compat[((size_t)b * kNS + i) * kNQ + j] = acc;
    }
}

__global__ __launch_bounds__(256) void init_kernel(double* __restrict__ z,
                                                   double* __restrict__ nu,
                                                   double* __restrict__ s,
                                                   double* __restrict__ lam)
{
    const int b = blockIdx.x;
    const int tid = threadIdx.x;
    for (int m = tid; m < kNZ; m += 256) {
        z[b*kNZ + m]   = 0.0;
        s[b*kNZ + m]   = 1.0;
        lam[b*kNZ + m] = 1.0;
    }
    if (tid < kNS) nu[b*kNS + tid] = 0.0;
}

// -------------------------------------------------------------------------
// One block per (b,a): build H_a = K + diag(1 + lam_a/s_a), compute r1_a,
// Gauss-Jordan invert in LDS (SPD, no pivoting), write Hinv and t_a=Hinv*r1_a
__global__ __launch_bounds__(256) void ipm_invert_kernel(
    const double* __restrict__ K64, const int* __restrict__ labels,
    const double* __restrict__ z, const double* __restrict__ nu,
    const double* __restrict__ s, const double* __restrict__ lam,
    double* __restrict__ Hinv, double* __restrict__ tvec)
{
    const int b = blockIdx.x / kNW;
    const int a = blockIdx.x % kNW;
    const int tid = threadIdx.x;

    __shared__ double H[kNS][kNS + 1];   // 80.8 KB
    __shared__ double colk[kNS];
    __shared__ double r1s[kNS];
    __shared__ double za[kNS], sa[kNS], la[kNS], da[kNS];
    __shared__ double red[256];

    const double* zb = z   + (size_t)b * kNZ;
    const double* sb = s   + (size_t)b * kNZ;
    const double* lb = lam + (size_t)b * kNZ;
    const double* Kb = K64 + (size_t)b * kNS * kNS;
    const int* labb  = labels + b * kNS;

    // mu = dot(s, lam)/kNZ over the whole batch state
    double part = 0.0;
    for (int m = tid; m < kNZ; m += 256) part += sb[m] * lb[m];
    red[tid] = part; __syncthreads();
    for (int off = 128; off > 0; off >>= 1) {
        if (tid < off) red[tid] += red[tid + off];
        __syncthreads();
    }
    const double mu = red[0] / kNZ;

    if (tid < kNS) {
        double zv = zb[tid * kNW + a];
        double sv = sb[tid * kNW + a];
        double lv = lb[tid * kNW + a];
        za[tid] = zv; sa[tid] = sv; la[tid] = lv; da[tid] = lv / sv;
    }
    __syncthreads();

    // Build H_a
    for (int idx = tid; idx < kNS * kNS; idx += 256) {
        int i = idx / kNS, j = idx - i * kNS;
        double v = Kb[idx];
        if (i == j) v += 1.0 + da[i];
        H[i][j] = v;
    }
    // r1_a[i] = -rd + (rc - lam*rp)/s  restricted to class a
    if (tid < kNS) {
        const int i = tid;
        double acc = 0.0;
        for (int j = 0; j < kNS; ++j) acc += Kb[i * kNS + j] * za[j];
        double yv = (labb[i] == a) ? 1.0 : 0.0;
        double rd = acc + za[i] + (-yv) + la[i] + nu[b * kNS + i];
        double rp = za[i] + sa[i] - 0.1 * yv;       // h = C_REG*y
        double rc = la[i] * sa[i] - 0.1 * mu;       // sigma = 0.1
        r1s[i] = -rd + (rc - la[i] * rp) / sa[i];
    }
    __syncthreads();

    // In-place Gauss-Jordan inverse (NR gaussj, no pivoting; SPD-safe)
    for (int k = 0; k < kNS; ++k) {
        double piv = H[k][k];
        __syncthreads();
        double pivinv = 1.0 / piv;
        if (tid < kNS) {
            if (tid == k) H[k][k] = pivinv;
            else          H[k][tid] *= pivinv;
        } else if (tid < 2 * kNS) {
            int i = tid - kNS;
            colk[i] = (i == k) ? 0.0 : H[i][k];
            if (i != k) H[i][k] = 0.0;
        }
        __syncthreads();
        for (int idx = tid; idx < kNS * kNS; idx += 256) {
            int i = idx / kNS, j = idx - i * kNS;
            if (i != k) H[i][j] -= colk[i] * H[k][j];
        }
        __syncthreads();
    }

    double* Hb = Hinv + ((size_t)(b * kNW + a)) * kNS * kNS;
    for (int idx = tid; idx < kNS * kNS; idx += 256) {
        int i = idx / kNS, j = idx - i * kNS;
        Hb[idx] = H[i][j];
    }
    if (tid < kNS) {
        double acc = 0.0;
        for (int j = 0; j < kNS; ++j) acc += H[tid][j] * r1s[j];
        tvec[(b * kNW + a) * kNS + tid] = acc;
    }
}

// -------------------------------------------------------------------------
// One block per b: S = sum_a Hinv_a, solve S*dnu = sum_a t_a + rp2,
// back out dz/ds/dlam, min-ratio step, update state.
__global__ __launch_bounds__(256) void ipm_schur_kernel(
    const int* __restrict__ labels,
    const double* __restrict__ Hinv, const double* __restrict__ tvec,
    double* __restrict__ z, double* __restrict__ nu,
    double* __restrict__ s, double* __restrict__ lam)
{
    const int b = blockIdx.x;
    const int tid = threadIdx.x;

    __shared__ double S[kNS][kNS + 1];   // col kNS = rhs; 80.8 KB
    __shared__ double colk[kNS];
    __shared__ double dzv[kNZ], dsv[kNZ], dlv[kNZ];  // 24 KB
    __shared__ double red[256];

    double* zb  = z   + (size_t)b * kNZ;
    double* sb  = s   + (size_t)b * kNZ;
    double* lb  = lam + (size_t)b * kNZ;
    double* nub = nu  + (size_t)b * kNS;
    const double* Hb = Hinv + (size_t)b * kNW * kNS * kNS;
    const double* tb = tvec + (size_t)b * kNW * kNS;
    const int* labb  = labels + b * kNS;

    // mu (same pre-update state as the invert kernel)
    double part = 0.0;
    for (int m = tid; m < kNZ; m += 256) part += sb[m] * lb[m];
    red[tid] = part; __syncthreads();
    for (int off = 128; off > 0; off >>= 1) {
        if (tid < off) red[tid] += red[tid + off];
        __syncthreads();
    }
    const double mu = red[0] / kNZ;

    // S = sum_a Hinv_a
    for (int idx = tid; idx < kNS * kNS; idx += 256) {
        double acc = 0.0;
        for (int a = 0; a < kNW; ++a) acc += Hb[(size_t)a * kNS * kNS + idx];
        S[idx / kNS][idx - (idx / kNS) * kNS] = acc;
    }
    // rhs = sum_a t_a + rp2,  rp2[i] = sum_a z[i,a]
    if (tid < kNS) {
        double acc = 0.0;
        for (int a = 0; a < kNW; ++a) acc += tb[a * kNS + tid];
        double rp2 = 0.0;
        for (int a = 0; a < kNW; ++a) rp2 += zb[tid * kNW + a];
        S[tid][kNS] = acc + rp2;
    }
    __syncthreads();

    // Gauss-Jordan solve with rhs column (no pivoting; SPD)
    for (int k = 0; k < kNS; ++k) {
        double piv = S[k][k];
        __syncthreads();
        double pivinv = 1.0 / piv;
        if (tid < kNS + 1) {
            S[k][tid] *= pivinv;                 // scales rhs too; S[k][k] -> 1
        } else if (tid >= 128 && tid < 128 + kNS) {
            int i = tid - 128;
            colk[i] = (i == k) ? 0.0 : S[i][k];
        }
        __syncthreads();
        for (int idx = tid; idx < kNS * (kNS + 1); idx += 256) {
            int i = idx / (kNS + 1), j = idx - i * (kNS + 1);
            if (i != k) S[i][j] -= colk[i] * S[k][j];
        }
        __syncthreads();
    }
    // dnu[i] = S[i][kNS]

    // dz[(i,a)] = t_a[i] - Hinv_a[i,:] . dnu
    for (int r = tid; r < kNZ; r += 256) {
        int a = r / kNS;
        int i = r - a * kNS;
        const double* Hrow = Hb + ((size_t)a * kNS + i) * kNS;
        double acc = tb[a * kNS + i];
        for (int j = 0; j < kNS; ++j) acc -= Hrow[j] * S[j][kNS];
        dzv[i * kNW + a] = acc;
    }
    __syncthreads();

    // ds, dlam, and step-length candidates
    double lmin = 1e300;
    for (int m = tid; m < kNZ; m += 256) {
        int i = m / kNW, a = m - (m / kNW) * kNW;
        double yv = (labb[i] == a) ? 1.0 : 0.0;
        double zv = zb[m], sv = sb[m], lv = lb[m];
        double rp = zv + sv - 0.1 * yv;
        double rc = lv * sv - 0.1 * mu;
        double dz = dzv[m];
        double ds = -rp - dz;
        double dl = (-rc - lv * ds) / sv;
        dsv[m] = ds; dlv[m] = dl;
        if (ds < 0.0) lmin = fmin(lmin, -sv / ds);
        if (dl < 0.0) lmin = fmin(lmin, -lv / dl);
    }
    red[tid] = lmin; __syncthreads();
    for (int off = 128; off > 0; off >>= 1) {
        if (tid < off) red[tid] = fmin(red[tid], red[tid + off]);
        __syncthreads();
    }
    const double alpha = fmin(1.0, 0.99 * red[0]);

    for (int m = tid; m < kNZ; m += 256) {
        zb[m] += alpha * dzv[m];
        sb[m] += alpha * dsv[m];
        lb[m] += alpha * dlv[m];
    }
    if (tid < kNS) nub[tid] += alpha * S[tid][kNS];
}

// -------------------------------------------------------------------------
// logits[b][q][n] = sum_s compat[b][s][q] * z[b][s*10+n]
__global__ __launch_bounds__(256) void logits_kernel(const float* __restrict__ compat,
                                                     const double* __restrict__ z,
                                                     float* __restrict__ out)
{
    const int b = blockIdx.x;
    const int tid = threadIdx.x;
    const float* cb = compat + (size_t)b * kNS * kNQ;
    const double* zb = z + (size_t)b * kNZ;
    __shared__ double zs[kNZ];
    for (int m = tid; m < kNZ; m += 256) zs[m] = zb[m];
    __syncthreads();
    for (int idx = tid; idx < kNQ * kNW; idx += 256) {
        int q = idx / kNW, n = idx - q * kNW;
        double acc = 0.0;
        for (int s2 = 0; s2 < kNS; ++s2)
            acc += (double)cb[(size_t)s2 * kNQ + q] * zs[s2 * kNW + n];
        out[(size_t)b * kNQ * kNW + idx] = (float)acc;
    }
}

// -------------------------------------------------------------------------
extern "C" void kernel_launch(void* const* d_in, const int* in_sizes, int n_in,
                              void* d_out, int out_size, void* d_ws, size_t ws_size,
                              hipStream_t stream)
{
    const float* sup    = (const float*)d_in[0];   // (32,10,10,512)
    const int*   labels = (const int*)  d_in[1];   // (32,10,10)
    const float* qry    = (const float*)d_in[2];   // (32,10,15,512)
    float* out = (float*)d_out;                    // (32,150,10) fp32

    char* ws = (char*)d_ws;
    size_t off = 0;
    auto alloc = [&](size_t bytes) -> void* {
        void* p = ws + off;
        off += (bytes + 255) & ~(size_t)255;
        return p;
    };
    double* K64    = (double*)alloc(sizeof(double) * kB * kNS * kNS);        // 2.56 MB
    double* z      = (double*)alloc(sizeof(double) * kB * kNZ);
    double* nu     = (double*)alloc(sizeof(double) * kB * kNS);
    double* s      = (double*)alloc(sizeof(double) * kB * kNZ);
    double* lam    = (double*)alloc(sizeof(double) * kB * kNZ);
    double* Hinv   = (double*)alloc(sizeof(double) * kB * kNW * kNS * kNS);  // 25.6 MB
    double* tvec   = (double*)alloc(sizeof(double) * kB * kNW * kNS);
    float*  compat = (float*) alloc(sizeof(float)  * kB * kNS * kNQ);        // 1.92 MB

    gram_kernel  <<<dim3(kNS, kB), 128, 0, stream>>>(sup, K64);
    compat_kernel<<<dim3(kNS, kB), 256, 0, stream>>>(sup, qry, compat);
    init_kernel  <<<kB, 256, 0, stream>>>(z, nu, s, lam);

    for (int it = 0; it < kIt; ++it) {
        ipm_invert_kernel<<<kB * kNW, 256, 0, stream>>>(K64, labels, z, nu, s, lam,
                                                        Hinv, tvec);
        ipm_schur_kernel <<<kB, 256, 0, stream>>>(labels, Hinv, tvec, z, nu, s, lam);
    }

    logits_kernel<<<kB, 256, 0, stream>>>(compat, z, out);
}